// Round 6
// baseline (125.529 us; speedup 1.0000x reference)
//
#include <hip/hip_runtime.h>
#include <math.h>

#define EPSF 1e-12f
#define DD 768
#define LL 576

typedef unsigned short u16;
typedef __attribute__((ext_vector_type(8))) short bf16x8;
typedef __attribute__((ext_vector_type(4))) float f32x4;

__device__ __forceinline__ u16 bf16h(float v) {
  unsigned u = __float_as_uint(v);
  return (u16)((u + 0x7FFFu + ((u >> 16) & 1u)) >> 16);
}

// split 8 floats -> packed hi uint4, lo uint4 (bf16 RNE, lo = v - hi)
__device__ __forceinline__ void split8(const float* v, uint4& ph, uint4& pl) {
  unsigned h[8], lo[8];
#pragma unroll
  for (int i = 0; i < 8; ++i) {
    unsigned u = __float_as_uint(v[i]);
    unsigned r = (u + 0x7FFFu + ((u >> 16) & 1u)) >> 16;
    h[i] = r;
    float rest = v[i] - __uint_as_float(r << 16);
    unsigned u2 = __float_as_uint(rest);
    lo[i] = (u2 + 0x7FFFu + ((u2 >> 16) & 1u)) >> 16;
  }
  ph = make_uint4(h[0] | (h[1] << 16), h[2] | (h[3] << 16),
                  h[4] | (h[5] << 16), h[6] | (h[7] << 16));
  pl = make_uint4(lo[0] | (lo[1] << 16), lo[2] | (lo[3] << 16),
                  lo[4] | (lo[5] << 16), lo[6] | (lo[7] << 16));
}

// Layout probe: D1 = (bcast m-label) x (ones) -> 32*row ; D2 = (ones) x
// (bcast n-label) -> 32*col. True (row,col) per acc reg, any convention.
__device__ __forceinline__ void probe_layout(int lane, int* rowz, int* colz) {
  bf16x8 va, v1;
  const short ml = (short)bf16h((float)(lane & 15));
  const short on = (short)0x3F80;  // bf16(1.0)
#pragma unroll
  for (int e = 0; e < 8; ++e) { va[e] = ml; v1[e] = on; }
  f32x4 z = {0.f, 0.f, 0.f, 0.f};
  f32x4 D1 = __builtin_amdgcn_mfma_f32_16x16x32_bf16(va, v1, z, 0, 0, 0);
  f32x4 D2 = __builtin_amdgcn_mfma_f32_16x16x32_bf16(v1, va, z, 0, 0, 0);
#pragma unroll
  for (int r = 0; r < 4; ++r) {
    rowz[r] = (int)(D1[r] * 0.03125f + 0.5f);
    colz[r] = (int)(D2[r] * 0.03125f + 0.5f);
  }
}

// ---------------------------------------------------------------------------
// kW: pre-split W into bf16 hi/lo A-fragments, fragment-major:
// wf[(strip*24 + s)*512 + lane*8 + j] = W[strip*16+(lane&15)][s*32+(lane>>4)*8+j]
// ---------------------------------------------------------------------------
__global__ __launch_bounds__(256) void kW(const float* __restrict__ w,
                                          u16* __restrict__ wfH,
                                          u16* __restrict__ wfL) {
  const int s = blockIdx.x;  // 0..23
  const int t = threadIdx.x;
  const int strip = t >> 6, lane = t & 63;
  const int k = strip * 16 + (lane & 15);
  const int d = s * 32 + (lane >> 4) * 8;
  float v[8];
  *(float4*)&v[0] = *(const float4*)(w + k * DD + d);
  *(float4*)&v[4] = *(const float4*)(w + k * DD + d + 4);
  uint4 ph, pl;
  split8(v, ph, pl);
  const size_t o = ((size_t)(strip * 24 + s) * 64 + lane) * 8;
  *(uint4*)(wfH + o) = ph;
  *(uint4*)(wfL + o) = pl;
}

// ---------------------------------------------------------------------------
// kA: per (n, 32-l tile): logits = W @ X via split-bf16 MFMA. 64-d chunks
// (12 iters, 3 barriers each). W from precomputed fragments; X reg-prefetched;
// one cooperative transpose+split per chunk. Probe scatter; softmax; att'.
// ---------------------------------------------------------------------------
__global__ __launch_bounds__(256) void kA(const float* __restrict__ x,
                                          const u16* __restrict__ wfH,
                                          const u16* __restrict__ wfL,
                                          u16* __restrict__ attH,
                                          u16* __restrict__ attL) {
  __shared__ __align__(16) char pool[18944];
  float (*raw)[36] = (float(*)[36])pool;       // [64d][32l+4] fp32, 9216B
  u16 (*Xh)[76] = (u16(*)[76])(pool + 9216);   // [32l][64d + pad12] 4864B
  u16 (*Xl)[76] = (u16(*)[76])(pool + 14080);  // 4864B
  float (*Ls)[36] = (float(*)[36])pool;        // [64k][32l+4] aliases raw
  __shared__ float redw[4][32];
  __shared__ float red8[8][32];
  __shared__ float colinv[32], colmax[32], colscale[32];

  const int b = blockIdx.x;
  const int n = b / 18, l0 = (b % 18) * 32;
  const int t = threadIdx.x;
  const int wv = t >> 6, lane = t & 63;

  int rowz[4], colz[4];
  probe_layout(lane, rowz, colz);

  f32x4 z = {0.f, 0.f, 0.f, 0.f};
  f32x4 acc[2] = {z, z};
  float ssq8[8] = {0.f, 0.f, 0.f, 0.f, 0.f, 0.f, 0.f, 0.f};

  const int dr = t >> 2;        // staging d-row 0..63
  const int cb = (t & 3) * 8;   // staging l-col base
  const int dblk = t >> 5;      // transpose d-block 0..7
  const int tl = t & 31;        // transpose l

  const float* xbase = x + (size_t)n * DD * LL + l0;
  const u16* wfHp = wfH + (size_t)wv * 12288 + (size_t)lane * 8;
  const u16* wfLp = wfL + (size_t)wv * 12288 + (size_t)lane * 8;

  float4 p0 = *(const float4*)(xbase + (size_t)dr * LL + cb);
  float4 p1 = *(const float4*)(xbase + (size_t)dr * LL + cb + 4);

  for (int it = 0; it < 12; ++it) {
    __syncthreads();  // prev iter LDS reads done
    *(float4*)&raw[dr][cb] = p0;
    *(float4*)&raw[dr][cb + 4] = p1;
    ssq8[0] = fmaf(p0.x, p0.x, ssq8[0]);
    ssq8[1] = fmaf(p0.y, p0.y, ssq8[1]);
    ssq8[2] = fmaf(p0.z, p0.z, ssq8[2]);
    ssq8[3] = fmaf(p0.w, p0.w, ssq8[3]);
    ssq8[4] = fmaf(p1.x, p1.x, ssq8[4]);
    ssq8[5] = fmaf(p1.y, p1.y, ssq8[5]);
    ssq8[6] = fmaf(p1.z, p1.z, ssq8[6]);
    ssq8[7] = fmaf(p1.w, p1.w, ssq8[7]);
    if (it < 11) {
      p0 = *(const float4*)(xbase + (size_t)((it + 1) * 64 + dr) * LL + cb);
      p1 = *(const float4*)(xbase + (size_t)((it + 1) * 64 + dr) * LL + cb + 4);
    }
    // A-fragments for the two 32-d sub-steps (L2/L3-hot)
    bf16x8 Ah0 = *(const bf16x8*)(wfHp + (size_t)(2 * it) * 512);
    bf16x8 Al0 = *(const bf16x8*)(wfLp + (size_t)(2 * it) * 512);
    bf16x8 Ah1 = *(const bf16x8*)(wfHp + (size_t)(2 * it + 1) * 512);
    bf16x8 Al1 = *(const bf16x8*)(wfLp + (size_t)(2 * it + 1) * 512);
    __syncthreads();  // raw ready
    // cooperative transpose+split: thread handles 8 d for one l
    {
      float v[8];
#pragma unroll
      for (int j = 0; j < 8; ++j) v[j] = raw[dblk * 8 + j][tl];
      uint4 ph, pl;
      split8(v, ph, pl);
      *(uint4*)&Xh[tl][dblk * 8] = ph;
      *(uint4*)&Xl[tl][dblk * 8] = pl;
    }
    __syncthreads();  // X ready
#pragma unroll
    for (int c = 0; c < 2; ++c) {
      const bf16x8 Ah = c ? Ah1 : Ah0;
      const bf16x8 Al = c ? Al1 : Al0;
#pragma unroll
      for (int lt = 0; lt < 2; ++lt) {
        const int bl = lt * 16 + (lane & 15);
        const int slot = (c * 4 + (lane >> 4)) * 8;
        bf16x8 Bh = *(const bf16x8*)&Xh[bl][slot];
        bf16x8 Bl = *(const bf16x8*)&Xl[bl][slot];
        acc[lt] = __builtin_amdgcn_mfma_f32_16x16x32_bf16(Ah, Bh, acc[lt], 0, 0, 0);
        acc[lt] = __builtin_amdgcn_mfma_f32_16x16x32_bf16(Ah, Bl, acc[lt], 0, 0, 0);
        acc[lt] = __builtin_amdgcn_mfma_f32_16x16x32_bf16(Al, Bh, acc[lt], 0, 0, 0);
      }
    }
  }

  // column sumsq: lanes sharing (lane&3) cover one 8-col group in this wave
#pragma unroll
  for (int i = 0; i < 8; ++i) {
    ssq8[i] += __shfl_xor(ssq8[i], 4, 64);
    ssq8[i] += __shfl_xor(ssq8[i], 8, 64);
    ssq8[i] += __shfl_xor(ssq8[i], 16, 64);
    ssq8[i] += __shfl_xor(ssq8[i], 32, 64);
  }
  if (lane < 4) {
#pragma unroll
    for (int i = 0; i < 8; ++i) redw[wv][lane * 8 + i] = ssq8[i];
  }
  __syncthreads();  // redw ready; also all loop LDS reads complete
  if (t < 32)
    colinv[t] = 1.f / fmaxf(
        sqrtf(redw[0][t] + redw[1][t] + redw[2][t] + redw[3][t]), EPSF);
  // scatter raw logits using PROBED positions (Ls aliases dead raw)
#pragma unroll
  for (int lt = 0; lt < 2; ++lt)
#pragma unroll
    for (int r = 0; r < 4; ++r)
      Ls[wv * 16 + rowz[r]][lt * 16 + colz[r]] = acc[lt][r];
  __syncthreads();

  // softmax over k per column; thread (q=t>>5, cl=t&31) owns 8 k's
  const int cl = t & 31, q = t >> 5;
  const float cinv = colinv[cl];
  float sv[8];
  float m = -1e30f;
#pragma unroll
  for (int i = 0; i < 8; ++i) {
    const float vv = Ls[q * 8 + i][cl] * cinv;
    sv[i] = vv;
    m = fmaxf(m, vv);
  }
  red8[q][cl] = m;
  __syncthreads();
  if (t < 32) {
    float mm = red8[0][t];
#pragma unroll
    for (int j = 1; j < 8; ++j) mm = fmaxf(mm, red8[j][t]);
    colmax[t] = mm;
  }
  __syncthreads();
  const float M = colmax[cl];
  float ssum = 0.f;
#pragma unroll
  for (int i = 0; i < 8; ++i) {
    const float e = __expf(sv[i] - M);
    sv[i] = e;
    ssum += e;
  }
  red8[q][cl] = ssum;
  __syncthreads();
  if (t < 32) {
    float ss = red8[0][t];
#pragma unroll
    for (int j = 1; j < 8; ++j) ss += red8[j][t];
    colscale[t] = colinv[t] / ss;
  }
  __syncthreads();
  const float cs = colscale[cl];
  u16* aH = attH + (size_t)n * 64 * LL + l0 + cl;
  u16* aL = attL + (size_t)n * 64 * LL + l0 + cl;
#pragma unroll
  for (int i = 0; i < 8; ++i) {
    const int k = q * 8 + i;
    const float e = sv[i] * cs;
    unsigned u = __float_as_uint(e);
    unsigned r = (u + 0x7FFFu + ((u >> 16) & 1u)) >> 16;
    const float rest = e - __uint_as_float(r << 16);
    aH[(size_t)k * LL] = (u16)r;
    aL[(size_t)k * LL] = bf16h(rest);
  }
}

// ---------------------------------------------------------------------------
// kB: per (n, 64-d tile): out[k][d] = sum_l att'[k][l] * x[d][l], split-bf16
// MFMA, 64-l chunks (9 iters), reg-prefetched. Fused per-(k,dtile) sumsq
// partials -> part[b][k] (deterministic, no atomics).
// ---------------------------------------------------------------------------
__global__ __launch_bounds__(256) void kB(const float* __restrict__ x,
                                          const u16* __restrict__ attH,
                                          const u16* __restrict__ attL,
                                          float* __restrict__ out,
                                          float* __restrict__ part) {
  __shared__ __align__(16) u16 AH[64][72];
  __shared__ __align__(16) u16 AL[64][72];
  __shared__ __align__(16) u16 Xh[64][72];
  __shared__ __align__(16) u16 Xl[64][72];
  const int b = blockIdx.x;
  const int n = b / 12, d0 = (b % 12) * 64;
  const int t = threadIdx.x;
  const int wv = t >> 6, lane = t & 63;

  int rowz[4], colz[4];
  probe_layout(lane, rowz, colz);

  f32x4 z = {0.f, 0.f, 0.f, 0.f};
  f32x4 acc[4] = {z, z, z, z};

  const int rk = t >> 2;        // staging row 0..63
  const int lb = (t & 3) * 16;  // l offset 0,16,32,48

  const u16* aHb = attH + ((size_t)n * 64 + rk) * LL + lb;
  const u16* aLb = attL + ((size_t)n * 64 + rk) * LL + lb;
  const float* xb = x + ((size_t)n * DD + d0 + rk) * LL + lb;

  uint4 pAH0 = *(const uint4*)aHb;
  uint4 pAH1 = *(const uint4*)(aHb + 8);
  uint4 pAL0 = *(const uint4*)aLb;
  uint4 pAL1 = *(const uint4*)(aLb + 8);
  float4 pX0 = *(const float4*)xb;
  float4 pX1 = *(const float4*)(xb + 4);
  float4 pX2 = *(const float4*)(xb + 8);
  float4 pX3 = *(const float4*)(xb + 12);

  for (int s = 0; s < 9; ++s) {
    __syncthreads();  // prev MFMA reads done
    *(uint4*)&AH[rk][lb] = pAH0;
    *(uint4*)&AH[rk][lb + 8] = pAH1;
    *(uint4*)&AL[rk][lb] = pAL0;
    *(uint4*)&AL[rk][lb + 8] = pAL1;
    {
      float v[8] = {pX0.x, pX0.y, pX0.z, pX0.w, pX1.x, pX1.y, pX1.z, pX1.w};
      uint4 ph, pl;
      split8(v, ph, pl);
      *(uint4*)&Xh[rk][lb] = ph;
      *(uint4*)&Xl[rk][lb] = pl;
      float v2[8] = {pX2.x, pX2.y, pX2.z, pX2.w, pX3.x, pX3.y, pX3.z, pX3.w};
      split8(v2, ph, pl);
      *(uint4*)&Xh[rk][lb + 8] = ph;
      *(uint4*)&Xl[rk][lb + 8] = pl;
    }
    if (s < 8) {
      const int lo = (s + 1) * 64;
      pAH0 = *(const uint4*)(aHb + lo);
      pAH1 = *(const uint4*)(aHb + lo + 8);
      pAL0 = *(const uint4*)(aLb + lo);
      pAL1 = *(const uint4*)(aLb + lo + 8);
      pX0 = *(const float4*)(xb + lo);
      pX1 = *(const float4*)(xb + lo + 4);
      pX2 = *(const float4*)(xb + lo + 8);
      pX3 = *(const float4*)(xb + lo + 12);
    }
    __syncthreads();  // staged
#pragma unroll
    for (int c = 0; c < 2; ++c) {
      const int ar = wv * 16 + (lane & 15);
      const int aoff = c * 32 + (lane >> 4) * 8;
      bf16x8 Ah = *(const bf16x8*)&AH[ar][aoff];
      bf16x8 Al = *(const bf16x8*)&AL[ar][aoff];
#pragma unroll
      for (int dt = 0; dt < 4; ++dt) {
        const int br = dt * 16 + (lane & 15);
        bf16x8 Bh = *(const bf16x8*)&Xh[br][aoff];
        bf16x8 Bl = *(const bf16x8*)&Xl[br][aoff];
        acc[dt] = __builtin_amdgcn_mfma_f32_16x16x32_bf16(Ah, Bh, acc[dt], 0, 0, 0);
        acc[dt] = __builtin_amdgcn_mfma_f32_16x16x32_bf16(Ah, Bl, acc[dt], 0, 0, 0);
        acc[dt] = __builtin_amdgcn_mfma_f32_16x16x32_bf16(Al, Bh, acc[dt], 0, 0, 0);
      }
    }
  }

  // store raw out using PROBED positions
  float* ob = out + ((size_t)n * 64 + wv * 16) * DD + d0;
#pragma unroll
  for (int dt = 0; dt < 4; ++dt)
#pragma unroll
    for (int r = 0; r < 4; ++r)
      ob[(size_t)rowz[r] * DD + dt * 16 + colz[r]] = acc[dt][r];

  // fused per-(k, d-tile) sumsq partial (deterministic)
#pragma unroll
  for (int r = 0; r < 4; ++r) {
    float s = 0.f;
#pragma unroll
    for (int dt = 0; dt < 4; ++dt) s = fmaf(acc[dt][r], acc[dt][r], s);
    s += __shfl_xor(s, 1, 64);
    s += __shfl_xor(s, 2, 64);
    s += __shfl_xor(s, 4, 64);
    s += __shfl_xor(s, 8, 64);
    if ((lane & 15) == 0)
      part[(size_t)b * 64 + wv * 16 + rowz[r]] = s;
  }
}

// ---------------------------------------------------------------------------
// Epilogue: kC2 sums 12 d-tile partials per (n,k) -> scales; kC3 applies.
// ---------------------------------------------------------------------------
__global__ __launch_bounds__(64) void kC2(const float* __restrict__ part,
                                          float* __restrict__ scale) {
  const int n = blockIdx.x;
  const int t = threadIdx.x;  // = k
  float ss = 0.f;
#pragma unroll
  for (int j = 0; j < 12; ++j) ss += part[(size_t)(n * 12 + j) * 64 + t];
  const float invk = 1.f / fmaxf(sqrtf(ss), EPSF);
  float r = ss * invk * invk;
#pragma unroll
  for (int off = 32; off >= 1; off >>= 1) r += __shfl_xor(r, off, 64);
  const float ginv = 1.f / fmaxf(sqrtf(r), EPSF);
  scale[n * 64 + t] = invk * ginv;
}

__global__ __launch_bounds__(256) void kC3(float* __restrict__ out,
                                           const float* __restrict__ scale) {
  const int i = blockIdx.x * 256 + threadIdx.x;
  const int row = i / 192;
  const float s = scale[row];
  float4 v = ((float4*)out)[i];
  v.x *= s; v.y *= s; v.z *= s; v.w *= s;
  ((float4*)out)[i] = v;
}

// ---------------------------------------------------------------------------
extern "C" void kernel_launch(void* const* d_in, const int* in_sizes, int n_in,
                              void* d_out, int out_size, void* d_ws, size_t ws_size,
                              hipStream_t stream) {
  const float* x = (const float*)d_in[0];  // [64,768,24,24]
  const float* w = (const float*)d_in[1];  // [64,768]
  float* out = (float*)d_out;              // [64, 64*768]

  u16* attH = (u16*)d_ws;                    // [64,64,576] bf16 hi
  u16* attL = attH + (size_t)2359296;        // lo plane
  u16* wfH = attL + (size_t)2359296;         // W fragments hi [4*24*64*8]
  u16* wfL = wfH + 49152;                    // W fragments lo
  float* part = (float*)(wfL + 49152);       // [768][64] sumsq partials
  float* scale = part + 49152;               // [4096]

  kW<<<24, 256, 0, stream>>>(w, wfH, wfL);
  kA<<<1152, 256, 0, stream>>>(x, wfH, wfL, attH, attL);
  kB<<<768, 256, 0, stream>>>(x, attH, attL, out, part);
  kC2<<<64, 64, 0, stream>>>(part, scale);
  kC3<<<3072, 256, 0, stream>>>(out, scale);
}

// Round 7
// 73.095 us; speedup vs baseline: 1.7173x; 1.7173x over previous
//
#include <hip/hip_runtime.h>
#include <math.h>

#define EPSF 1e-12f
#define DD 768
#define LL 576

typedef unsigned short u16;
typedef __attribute__((ext_vector_type(8))) short bf16x8;
typedef __attribute__((ext_vector_type(4))) float f32x4;

__device__ __forceinline__ u16 bf16h(float v) {
  unsigned u = __float_as_uint(v);
  return (u16)((u + 0x7FFFu + ((u >> 16) & 1u)) >> 16);
}

// split 8 floats -> packed hi uint4, lo uint4 (bf16 RNE, lo = v - hi)
__device__ __forceinline__ void split8(const float* v, uint4& ph, uint4& pl) {
  unsigned h[8], lo[8];
#pragma unroll
  for (int i = 0; i < 8; ++i) {
    unsigned u = __float_as_uint(v[i]);
    unsigned r = (u + 0x7FFFu + ((u >> 16) & 1u)) >> 16;
    h[i] = r;
    float rest = v[i] - __uint_as_float(r << 16);
    unsigned u2 = __float_as_uint(rest);
    lo[i] = (u2 + 0x7FFFu + ((u2 >> 16) & 1u)) >> 16;
  }
  ph = make_uint4(h[0] | (h[1] << 16), h[2] | (h[3] << 16),
                  h[4] | (h[5] << 16), h[6] | (h[7] << 16));
  pl = make_uint4(lo[0] | (lo[1] << 16), lo[2] | (lo[3] << 16),
                  lo[4] | (lo[5] << 16), lo[6] | (lo[7] << 16));
}

// split 4 floats -> packed hi uint2, lo uint2
__device__ __forceinline__ void split4(const float* v, uint2& ph, uint2& pl) {
  unsigned h[4], lo[4];
#pragma unroll
  for (int i = 0; i < 4; ++i) {
    unsigned u = __float_as_uint(v[i]);
    unsigned r = (u + 0x7FFFu + ((u >> 16) & 1u)) >> 16;
    h[i] = r;
    float rest = v[i] - __uint_as_float(r << 16);
    unsigned u2 = __float_as_uint(rest);
    lo[i] = (u2 + 0x7FFFu + ((u2 >> 16) & 1u)) >> 16;
  }
  ph = make_uint2(h[0] | (h[1] << 16), h[2] | (h[3] << 16));
  pl = make_uint2(lo[0] | (lo[1] << 16), lo[2] | (lo[3] << 16));
}

// Layout probe: D1 = (bcast m-label) x (ones) -> 32*row ; D2 = (ones) x
// (bcast n-label) -> 32*col. True (row,col) per acc reg, any convention.
__device__ __forceinline__ void probe_layout(int lane, int* rowz, int* colz) {
  bf16x8 va, v1;
  const short ml = (short)bf16h((float)(lane & 15));
  const short on = (short)0x3F80;  // bf16(1.0)
#pragma unroll
  for (int e = 0; e < 8; ++e) { va[e] = ml; v1[e] = on; }
  f32x4 z = {0.f, 0.f, 0.f, 0.f};
  f32x4 D1 = __builtin_amdgcn_mfma_f32_16x16x32_bf16(va, v1, z, 0, 0, 0);
  f32x4 D2 = __builtin_amdgcn_mfma_f32_16x16x32_bf16(v1, va, z, 0, 0, 0);
#pragma unroll
  for (int r = 0; r < 4; ++r) {
    rowz[r] = (int)(D1[r] * 0.03125f + 0.5f);
    colz[r] = (int)(D2[r] * 0.03125f + 0.5f);
  }
}

// ---------------------------------------------------------------------------
// kW: pre-split W into bf16 hi/lo A-fragments, fragment-major:
// wf[((strip*24 + s)*64 + lane)*8 + j] = W[strip*16+(lane&15)][s*32+(lane>>4)*8+j]
// ---------------------------------------------------------------------------
__global__ __launch_bounds__(256) void kW(const float* __restrict__ w,
                                          u16* __restrict__ wfH,
                                          u16* __restrict__ wfL) {
  const int s = blockIdx.x;  // 0..23
  const int t = threadIdx.x;
  const int strip = t >> 6, lane = t & 63;
  const int k = strip * 16 + (lane & 15);
  const int d = s * 32 + (lane >> 4) * 8;
  float v[8];
  *(float4*)&v[0] = *(const float4*)(w + k * DD + d);
  *(float4*)&v[4] = *(const float4*)(w + k * DD + d + 4);
  uint4 ph, pl;
  split8(v, ph, pl);
  const size_t o = ((size_t)(strip * 24 + s) * 64 + lane) * 8;
  *(uint4*)(wfH + o) = ph;
  *(uint4*)(wfL + o) = pl;
}

// ---------------------------------------------------------------------------
// kA: per (n, 32-l tile): logits = W @ X via split-bf16 MFMA.  (round-5 form)
// W from precomputed fragments (global, L2-hot). X reg-prefetched one step
// ahead; LDS transpose+split once per step. Probe-based scatter; softmax.
// ---------------------------------------------------------------------------
__global__ __launch_bounds__(256) void kA(const float* __restrict__ x,
                                          const u16* __restrict__ wfH,
                                          const u16* __restrict__ wfL,
                                          u16* __restrict__ attH,
                                          u16* __restrict__ attL) {
  __shared__ __align__(16) char pool[9728];
  float (*raw)[36] = (float(*)[36])pool;       // [32d][32l+4] fp32
  u16 (*Xh)[40] = (u16(*)[40])(pool + 4608);   // [32l][32d swizzled]+pad
  u16 (*Xl)[40] = (u16(*)[40])(pool + 7168);
  float (*Ls)[36] = (float(*)[36])pool;        // [64k][32l+4] aliases pool
  __shared__ float red8[8][32];
  __shared__ float colinv[32], colmax[32], colscale[32];

  const int b = blockIdx.x;
  const int n = b / 18, l0 = (b % 18) * 32;
  const int t = threadIdx.x;
  const int wv = t >> 6, lane = t & 63;

  int rowz[4], colz[4];
  probe_layout(lane, rowz, colz);

  f32x4 z = {0.f, 0.f, 0.f, 0.f};
  f32x4 acc[2] = {z, z};
  float ssq4[4] = {0.f, 0.f, 0.f, 0.f};

  const int xd = t >> 3;        // 0..31 staging row
  const int xl = (t & 7) * 4;   // staging l quad
  const int tl = lane & 31;     // transpose l
  const int half = lane >> 5;   // transpose d-half

  const float* xbase = x + (size_t)n * DD * LL + l0;
  const u16* wfHp = wfH + ((size_t)wv * 24 * 64 + lane) * 8;
  const u16* wfLp = wfL + ((size_t)wv * 24 * 64 + lane) * 8;

  float4 pre = *(const float4*)(xbase + (size_t)xd * LL + xl);

  for (int s = 0; s < 24; ++s) {
    __syncthreads();  // prev transpose raw-reads + prev MFMA Xh/Xl-reads done
    *(float4*)&raw[xd][xl] = pre;
    ssq4[0] = fmaf(pre.x, pre.x, ssq4[0]);
    ssq4[1] = fmaf(pre.y, pre.y, ssq4[1]);
    ssq4[2] = fmaf(pre.z, pre.z, ssq4[2]);
    ssq4[3] = fmaf(pre.w, pre.w, ssq4[3]);
    if (s < 23)
      pre = *(const float4*)(xbase + (size_t)((s + 1) * 32 + xd) * LL + xl);
    bf16x8 Ah = *(const bf16x8*)(wfHp + (size_t)s * 512);
    bf16x8 Alo = *(const bf16x8*)(wfLp + (size_t)s * 512);
    __syncthreads();  // raw ready
    // transpose+split: thread (dg=wv, half, tl) handles 4 d-elements
    {
      float v[4];
#pragma unroll
      for (int j = 0; j < 4; ++j) v[j] = raw[wv * 8 + half * 4 + j][tl];
      uint2 ph, pl;
      split4(v, ph, pl);
      const int pb = (wv ^ ((tl >> 3) & 3)) * 8 + half * 4;
      *(uint2*)&Xh[tl][pb] = ph;
      *(uint2*)&Xl[tl][pb] = pl;
    }
    __syncthreads();  // Xh/Xl ready
#pragma unroll
    for (int lt = 0; lt < 2; ++lt) {
      const int bl = lt * 16 + (lane & 15);
      const int pb = ((lane >> 4) ^ ((bl >> 3) & 3)) * 8;
      bf16x8 Bh = *(const bf16x8*)&Xh[bl][pb];
      bf16x8 Bl = *(const bf16x8*)&Xl[bl][pb];
      acc[lt] = __builtin_amdgcn_mfma_f32_16x16x32_bf16(Ah, Bh, acc[lt], 0, 0, 0);
      acc[lt] = __builtin_amdgcn_mfma_f32_16x16x32_bf16(Ah, Bl, acc[lt], 0, 0, 0);
      acc[lt] = __builtin_amdgcn_mfma_f32_16x16x32_bf16(Alo, Bh, acc[lt], 0, 0, 0);
    }
  }

  // ssq reduce across xd-within-wave (lane bits 3,4,5); cg = lane&7
#pragma unroll
  for (int i = 0; i < 4; ++i) {
    ssq4[i] += __shfl_xor(ssq4[i], 8, 64);
    ssq4[i] += __shfl_xor(ssq4[i], 16, 64);
    ssq4[i] += __shfl_xor(ssq4[i], 32, 64);
  }
  if (lane < 8) {
#pragma unroll
    for (int i = 0; i < 4; ++i) red8[wv][lane * 4 + i] = ssq4[i];
  }
  __syncthreads();  // also guards Ls scatter vs last MFMA reads
  if (t < 32)
    colinv[t] =
        1.f / fmaxf(sqrtf(red8[0][t] + red8[1][t] + red8[2][t] + red8[3][t]), EPSF);
  // scatter raw logits using PROBED positions (Ls aliases dead staging pool)
#pragma unroll
  for (int lt = 0; lt < 2; ++lt)
#pragma unroll
    for (int r = 0; r < 4; ++r)
      Ls[wv * 16 + rowz[r]][lt * 16 + colz[r]] = acc[lt][r];
  __syncthreads();

  // softmax over k per column; thread (q=t>>5, cl=t&31) owns 8 k's
  const int cl = t & 31, q = t >> 5;
  const float cinv = colinv[cl];
  float sv[8];
  float m = -1e30f;
#pragma unroll
  for (int i = 0; i < 8; ++i) {
    const float vv = Ls[q * 8 + i][cl] * cinv;
    sv[i] = vv;
    m = fmaxf(m, vv);
  }
  red8[q][cl] = m;
  __syncthreads();
  if (t < 32) {
    float mm = red8[0][t];
#pragma unroll
    for (int j = 1; j < 8; ++j) mm = fmaxf(mm, red8[j][t]);
    colmax[t] = mm;
  }
  __syncthreads();
  const float M = colmax[cl];
  float ssum = 0.f;
#pragma unroll
  for (int i = 0; i < 8; ++i) {
    const float e = __expf(sv[i] - M);
    sv[i] = e;
    ssum += e;
  }
  red8[q][cl] = ssum;
  __syncthreads();
  if (t < 32) {
    float ss = red8[0][t];
#pragma unroll
    for (int j = 1; j < 8; ++j) ss += red8[j][t];
    colscale[t] = colinv[t] / ss;
  }
  __syncthreads();
  const float cs = colscale[cl];
  u16* aH = attH + (size_t)n * 64 * LL + l0 + cl;
  u16* aL = attL + (size_t)n * 64 * LL + l0 + cl;
#pragma unroll
  for (int i = 0; i < 8; ++i) {
    const int k = q * 8 + i;
    const float e = sv[i] * cs;
    unsigned u = __float_as_uint(e);
    unsigned r = (u + 0x7FFFu + ((u >> 16) & 1u)) >> 16;
    const float rest = e - __uint_as_float(r << 16);
    aH[(size_t)k * LL] = (u16)r;
    aL[(size_t)k * LL] = bf16h(rest);
  }
}

// ---------------------------------------------------------------------------
// kB: per (n, 64-d tile): out[k][d] = sum_l att'[k][l] * x[d][l], split-bf16
// MFMA, reg-prefetched staging (round-5 form). Probe-based output positions.
// Fused per-(k, d-tile) sumsq partials -> part[b][k] (deterministic).
// ---------------------------------------------------------------------------
__global__ __launch_bounds__(256) void kB(const float* __restrict__ x,
                                          const u16* __restrict__ attH,
                                          const u16* __restrict__ attL,
                                          float* __restrict__ out,
                                          float* __restrict__ part) {
  __shared__ __align__(16) u16 AH[64][40];
  __shared__ __align__(16) u16 AL[64][40];
  __shared__ __align__(16) u16 Xh[64][40];
  __shared__ __align__(16) u16 Xl[64][40];
  const int b = blockIdx.x;
  const int n = b / 12, d0 = (b % 12) * 64;
  const int t = threadIdx.x;
  const int wv = t >> 6, lane = t & 63;

  int rowz[4], colz[4];
  probe_layout(lane, rowz, colz);

  f32x4 z = {0.f, 0.f, 0.f, 0.f};
  f32x4 acc[4] = {z, z, z, z};

  const int rk = t >> 2;       // staging row 0..63
  const int lb = (t & 3) * 8;  // l offset 0,8,16,24

  const u16* aHb = attH + ((size_t)n * 64 + rk) * LL + lb;
  const u16* aLb = attL + ((size_t)n * 64 + rk) * LL + lb;
  const float* xb = x + ((size_t)n * DD + d0 + rk) * LL + lb;

  uint4 pAH = *(const uint4*)aHb;
  uint4 pAL = *(const uint4*)aLb;
  float4 pX0 = *(const float4*)xb;
  float4 pX1 = *(const float4*)(xb + 4);

  for (int s = 0; s < 18; ++s) {
    __syncthreads();  // prev MFMA reads done
    *(uint4*)&AH[rk][lb] = pAH;
    *(uint4*)&AL[rk][lb] = pAL;
    {
      float v[8] = {pX0.x, pX0.y, pX0.z, pX0.w, pX1.x, pX1.y, pX1.z, pX1.w};
      uint4 ph, pl;
      split8(v, ph, pl);
      *(uint4*)&Xh[rk][lb] = ph;
      *(uint4*)&Xl[rk][lb] = pl;
    }
    if (s < 17) {
      const int lo = (s + 1) * 32;
      pAH = *(const uint4*)(aHb + lo);
      pAL = *(const uint4*)(aLb + lo);
      pX0 = *(const float4*)(xb + lo);
      pX1 = *(const float4*)(xb + lo + 4);
    }
    __syncthreads();  // staged
    const int ar = wv * 16 + (lane & 15);
    const int ab = (lane >> 4) * 8;
    bf16x8 Ah = *(const bf16x8*)&AH[ar][ab];
    bf16x8 Alo = *(const bf16x8*)&AL[ar][ab];
#pragma unroll
    for (int dt = 0; dt < 4; ++dt) {
      const int br = dt * 16 + (lane & 15);
      bf16x8 Bh = *(const bf16x8*)&Xh[br][ab];
      bf16x8 Bl = *(const bf16x8*)&Xl[br][ab];
      acc[dt] = __builtin_amdgcn_mfma_f32_16x16x32_bf16(Ah, Bh, acc[dt], 0, 0, 0);
      acc[dt] = __builtin_amdgcn_mfma_f32_16x16x32_bf16(Ah, Bl, acc[dt], 0, 0, 0);
      acc[dt] = __builtin_amdgcn_mfma_f32_16x16x32_bf16(Alo, Bh, acc[dt], 0, 0, 0);
    }
  }

  // store raw out using PROBED positions
  float* ob = out + ((size_t)n * 64 + wv * 16) * DD + d0;
#pragma unroll
  for (int dt = 0; dt < 4; ++dt)
#pragma unroll
    for (int r = 0; r < 4; ++r)
      ob[(size_t)rowz[r] * DD + dt * 16 + colz[r]] = acc[dt][r];

  // fused per-(k, d-tile) sumsq partial (deterministic, no atomics).
  // Lanes sharing rowz[r] are the 16 lanes of a (lane>>4) group (validated
  // on HW in round 6: PASS with this reduction).
#pragma unroll
  for (int r = 0; r < 4; ++r) {
    float s = 0.f;
#pragma unroll
    for (int dt = 0; dt < 4; ++dt) s = fmaf(acc[dt][r], acc[dt][r], s);
    s += __shfl_xor(s, 1, 64);
    s += __shfl_xor(s, 2, 64);
    s += __shfl_xor(s, 4, 64);
    s += __shfl_xor(s, 8, 64);
    if ((lane & 15) == 0)
      part[(size_t)b * 64 + wv * 16 + rowz[r]] = s;
  }
}

// ---------------------------------------------------------------------------
// Epilogue: kC2 sums 12 d-tile partials per (n,k) -> scales; kC3 applies.
// ---------------------------------------------------------------------------
__global__ __launch_bounds__(64) void kC2(const float* __restrict__ part,
                                          float* __restrict__ scale) {
  const int n = blockIdx.x;
  const int t = threadIdx.x;  // = k
  float ss = 0.f;
#pragma unroll
  for (int j = 0; j < 12; ++j) ss += part[(size_t)(n * 12 + j) * 64 + t];
  const float invk = 1.f / fmaxf(sqrtf(ss), EPSF);
  float r = ss * invk * invk;
#pragma unroll
  for (int off = 32; off >= 1; off >>= 1) r += __shfl_xor(r, off, 64);
  const float ginv = 1.f / fmaxf(sqrtf(r), EPSF);
  scale[n * 64 + t] = invk * ginv;
}

__global__ __launch_bounds__(256) void kC3(float* __restrict__ out,
                                           const float* __restrict__ scale) {
  const int i = blockIdx.x * 256 + threadIdx.x;
  const int row = i / 192;
  const float s = scale[row];
  float4 v = ((float4*)out)[i];
  v.x *= s; v.y *= s; v.z *= s; v.w *= s;
  ((float4*)out)[i] = v;
}

// ---------------------------------------------------------------------------
extern "C" void kernel_launch(void* const* d_in, const int* in_sizes, int n_in,
                              void* d_out, int out_size, void* d_ws, size_t ws_size,
                              hipStream_t stream) {
  const float* x = (const float*)d_in[0];  // [64,768,24,24]
  const float* w = (const float*)d_in[1];  // [64,768]
  float* out = (float*)d_out;              // [64, 64*768]

  u16* attH = (u16*)d_ws;                    // [64,64,576] bf16 hi
  u16* attL = attH + (size_t)2359296;        // lo plane
  u16* wfH = attL + (size_t)2359296;         // W fragments hi [4*24*64*8]
  u16* wfL = wfH + 49152;                    // W fragments lo
  float* part = (float*)(wfL + 49152);       // [768][64] sumsq partials
  float* scale = part + 49152;               // [4096]

  kW<<<24, 256, 0, stream>>>(w, wfH, wfL);
  kA<<<1152, 256, 0, stream>>>(x, wfH, wfL, attH, attL);
  kB<<<768, 256, 0, stream>>>(x, attH, attL, out, part);
  kC2<<<64, 64, 0, stream>>>(part, scale);
  kC3<<<3072, 256, 0, stream>>>(out, scale);
}